// Round 1
// baseline (274.824 us; speedup 1.0000x reference)
//
#include <hip/hip_runtime.h>
#include <hip/hip_bf16.h>

#define BSZ 4
#define S1v 2048
#define S2v 2048
#define DM 512
#define NH 8
#define HD 64
#define SCALE 0.044194173824159216f
#define L2E 1.4426950408889634f
#define NEGB (-1e30f)

typedef __bf16 bf16x8 __attribute__((ext_vector_type(8)));
typedef float f32x4 __attribute__((ext_vector_type(4)));

__device__ __forceinline__ unsigned short f2bf(float f) {
  union { float f; unsigned u; } v; v.f = f;
  unsigned r = v.u + 0x7FFFu + ((v.u >> 16) & 1u);
  return (unsigned short)(r >> 16);
}

// ---------------- weight transpose + cast: Wt[n][k] = bf16(W[k][n]) ------------
__global__ __launch_bounds__(256)
void wtrans(const float* __restrict__ W, unsigned short* __restrict__ Wt) {
  __shared__ float tile[32][33];
  const int tx = threadIdx.x, ty = threadIdx.y;     // block (32,8)
  const int n0 = blockIdx.x * 32, k0 = blockIdx.y * 32;
#pragma unroll
  for (int i = 0; i < 32; i += 8)
    tile[ty + i][tx] = W[(size_t)(k0 + ty + i) * DM + n0 + tx];
  __syncthreads();
#pragma unroll
  for (int i = 0; i < 32; i += 8)
    Wt[(size_t)(n0 + ty + i) * DM + k0 + tx] = f2bf(tile[tx][ty + i]);
}

// ---------------- projection GEMM: Y(bf16)[8192x512] = X(f32) @ W + bias -------
// Wt is pre-transposed bf16 [n][k]. Optionally also writes Yt = per-head
// transposed copy laid out [b][h][hd][s2] for the attention V staging.
__global__ __launch_bounds__(256)
void proj_gemm(const float* __restrict__ X, const unsigned short* __restrict__ Wt,
               const float* __restrict__ bias, unsigned short* __restrict__ Y,
               unsigned short* __restrict__ Yt) {
  __shared__ unsigned short Xs[128][72];
  __shared__ unsigned short Ws[128][72];
  const int tid = threadIdx.x;
  const int wv = tid >> 6, lane = tid & 63;
  const int ln = lane & 15, qd = lane >> 4, q8 = qd * 8;
  const int wm = (wv >> 1) * 64, wn = (wv & 1) * 64;
  const int m0 = blockIdx.x * 128, n0 = blockIdx.y * 128;
  f32x4 acc[4][4] = {};
  for (int k0 = 0; k0 < DM; k0 += 64) {
    __syncthreads();
#pragma unroll
    for (int i = 0; i < 8; ++i) {                   // X tile 128x64 f32 -> bf16
      int cid = tid + i * 256;
      int r = cid >> 4, c4 = (cid & 15) * 4;
      const float4 v = *(const float4*)(X + (size_t)(m0 + r) * DM + k0 + c4);
      ushort4 bv;
      bv.x = f2bf(v.x); bv.y = f2bf(v.y); bv.z = f2bf(v.z); bv.w = f2bf(v.w);
      *(ushort4*)&Xs[r][c4] = bv;
    }
#pragma unroll
    for (int i = 0; i < 4; ++i) {                   // Wt tile 128x64 bf16 copy
      int cid = tid + i * 256;
      int r = cid >> 3, ch = (cid & 7) * 8;
      *(uint4*)&Ws[r][ch] = *(const uint4*)(Wt + (size_t)(n0 + r) * DM + k0 + ch);
    }
    __syncthreads();
#pragma unroll
    for (int kk = 0; kk < 2; ++kk) {
      bf16x8 aF[4], bF[4];
#pragma unroll
      for (int i = 0; i < 4; ++i)
        aF[i] = *(const bf16x8*)&Xs[wm + 16 * i + ln][kk * 32 + q8];
#pragma unroll
      for (int j = 0; j < 4; ++j)
        bF[j] = *(const bf16x8*)&Ws[wn + 16 * j + ln][kk * 32 + q8];
#pragma unroll
      for (int i = 0; i < 4; ++i)
#pragma unroll
        for (int j = 0; j < 4; ++j)
          acc[i][j] = __builtin_amdgcn_mfma_f32_16x16x32_bf16(aF[i], bF[j], acc[i][j], 0, 0, 0);
    }
  }
#pragma unroll
  for (int i = 0; i < 4; ++i)
#pragma unroll
    for (int j = 0; j < 4; ++j) {
      const int n = n0 + wn + 16 * j + ln;
      const float bb = bias[n];
#pragma unroll
      for (int r = 0; r < 4; ++r) {
        const int m = m0 + wm + 16 * i + qd * 4 + r;
        const unsigned short bv = f2bf(acc[i][j][r] + bb);
        Y[(size_t)m * DM + n] = bv;
        if (Yt != nullptr) {
          const int b = m >> 11, s = m & 2047, hh = n >> 6, c = n & 63;
          Yt[((size_t)((b * NH + hh) * HD + c)) * (size_t)S2v + s] = bv;
        }
      }
    }
}

// ---------------- flash attention (V = K), masked, online softmax --------------
// grid (S1/64, BSZ*NH), block 256 (4 waves x 16 Q-rows each)
__global__ __launch_bounds__(256)
void flash_attn(const unsigned short* __restrict__ Qb, const unsigned short* __restrict__ Kb,
                const unsigned short* __restrict__ Kt, const int* __restrict__ m1,
                const int* __restrict__ m2, float* __restrict__ attn) {
  __shared__ unsigned short Qs[64][72];
  __shared__ unsigned short Ks[128][72];
  __shared__ unsigned short Vts[64][136];
  __shared__ unsigned short Ps[4][16][136];
  __shared__ int m2s[128];

  const int tid = threadIdx.x;
  const int wv = tid >> 6, lane = tid & 63;
  const int ln = lane & 15, qd = lane >> 4, q8 = qd * 8;
  const int bh = blockIdx.y;
  const int b = bh >> 3, h = bh & 7;
  const int q0 = blockIdx.x * 64;

#pragma unroll
  for (int i = 0; i < 2; ++i) {                     // Q tile 64x64
    int cid = tid + i * 256;
    int r = cid >> 3, ch = (cid & 7) * 8;
    *(uint4*)&Qs[r][ch] =
        *(const uint4*)(Qb + ((size_t)(b * S1v + q0 + r)) * DM + h * HD + ch);
  }

  bool uni[4];
#pragma unroll
  for (int r = 0; r < 4; ++r)
    uni[r] = (m1[b * S1v + q0 + wv * 16 + qd * 4 + r] == 0);

  float mrow[4], lrow[4];
#pragma unroll
  for (int r = 0; r < 4; ++r) { mrow[r] = NEGB; lrow[r] = 0.f; }
  f32x4 O[4] = {};

  for (int s0 = 0; s0 < S2v; s0 += 128) {
    __syncthreads();
#pragma unroll
    for (int i = 0; i < 4; ++i) {                   // K tile 128x64
      int cid = tid + i * 256;
      int r = cid >> 3, ch = (cid & 7) * 8;
      *(uint4*)&Ks[r][ch] =
          *(const uint4*)(Kb + ((size_t)(b * S2v + s0 + r)) * DM + h * HD + ch);
    }
#pragma unroll
    for (int i = 0; i < 4; ++i) {                   // V^T tile 64x128 from Kt
      int cid = tid + i * 256;
      int r = cid >> 4, ch = (cid & 15) * 8;
      *(uint4*)&Vts[r][ch] =
          *(const uint4*)(Kt + ((size_t)(bh * HD + r)) * (size_t)S2v + s0 + ch);
    }
    if (tid < 128) m2s[tid] = m2[b * S2v + s0 + tid];
    __syncthreads();

    // S = Q K^T  (per wave: 16 rows x 128 cols)
    const bf16x8 aQ0 = *(const bf16x8*)&Qs[wv * 16 + ln][q8];
    const bf16x8 aQ1 = *(const bf16x8*)&Qs[wv * 16 + ln][32 + q8];
    f32x4 sc[8];
#pragma unroll
    for (int j = 0; j < 8; ++j) {
      const bf16x8 b0 = *(const bf16x8*)&Ks[16 * j + ln][q8];
      const bf16x8 b1 = *(const bf16x8*)&Ks[16 * j + ln][32 + q8];
      f32x4 z = {};
      z = __builtin_amdgcn_mfma_f32_16x16x32_bf16(aQ0, b0, z, 0, 0, 0);
      sc[j] = __builtin_amdgcn_mfma_f32_16x16x32_bf16(aQ1, b1, z, 0, 0, 0);
    }

    float p[8][4], mloc[4];
#pragma unroll
    for (int r = 0; r < 4; ++r) mloc[r] = NEGB;
#pragma unroll
    for (int j = 0; j < 8; ++j) {
      const bool ok = (m2s[16 * j + ln] != 0);
#pragma unroll
      for (int r = 0; r < 4; ++r) {
        float sv = ok ? sc[j][r] * SCALE : NEGB;
        sv = uni[r] ? 0.0f : sv;                    // m1==0 row: uniform over ALL cols
        p[j][r] = sv;
        mloc[r] = fmaxf(mloc[r], sv);
      }
    }
#pragma unroll
    for (int r = 0; r < 4; ++r)
#pragma unroll
      for (int msk = 1; msk < 16; msk <<= 1)
        mloc[r] = fmaxf(mloc[r], __shfl_xor(mloc[r], msk, 16));

    float alpha[4], lsum[4];
#pragma unroll
    for (int r = 0; r < 4; ++r) {
      const float mnew = fmaxf(mrow[r], mloc[r]);
      alpha[r] = __builtin_amdgcn_exp2f((mrow[r] - mnew) * L2E);
      mrow[r] = mnew;
      float s = 0.f;
#pragma unroll
      for (int j = 0; j < 8; ++j) {
        const float e = __builtin_amdgcn_exp2f((p[j][r] - mnew) * L2E);
        p[j][r] = e;
        s += e;
      }
      lsum[r] = s;
    }
#pragma unroll
    for (int r = 0; r < 4; ++r) {
#pragma unroll
      for (int msk = 1; msk < 16; msk <<= 1)
        lsum[r] += __shfl_xor(lsum[r], msk, 16);
      lrow[r] = lrow[r] * alpha[r] + lsum[r];
    }

    // C-layout -> A-layout via per-wave LDS round-trip
#pragma unroll
    for (int j = 0; j < 8; ++j)
#pragma unroll
      for (int r = 0; r < 4; ++r)
        Ps[wv][qd * 4 + r][16 * j + ln] = f2bf(p[j][r]);
    __asm__ volatile("s_waitcnt lgkmcnt(0)" ::: "memory");

#pragma unroll
    for (int jn = 0; jn < 4; ++jn)
#pragma unroll
      for (int r = 0; r < 4; ++r)
        O[jn][r] *= alpha[r];

#pragma unroll
    for (int kk = 0; kk < 4; ++kk) {
      const bf16x8 aP = *(const bf16x8*)&Ps[wv][ln][kk * 32 + q8];
#pragma unroll
      for (int jn = 0; jn < 4; ++jn) {
        const bf16x8 bV = *(const bf16x8*)&Vts[16 * jn + ln][kk * 32 + q8];
        O[jn] = __builtin_amdgcn_mfma_f32_16x16x32_bf16(aP, bV, O[jn], 0, 0, 0);
      }
    }
  }

  float inv[4];
#pragma unroll
  for (int r = 0; r < 4; ++r) inv[r] = lrow[r] > 0.f ? 1.0f / lrow[r] : 0.f;
#pragma unroll
  for (int jn = 0; jn < 4; ++jn)
#pragma unroll
    for (int r = 0; r < 4; ++r) {
      const int m = q0 + wv * 16 + qd * 4 + r;
      attn[((size_t)(b * S1v + m)) * DM + h * HD + 16 * jn + ln] = O[jn][r] * inv[r];
    }
}

// ---------------- fused LN2(attn + LN1(attn + modal1)) ------------------------
__global__ __launch_bounds__(128)
void ln_fused(const float* __restrict__ attn, const float* __restrict__ modal1,
              const float* __restrict__ g1, const float* __restrict__ b1,
              const float* __restrict__ g2, const float* __restrict__ b2,
              float* __restrict__ out) {
  __shared__ float red[4];
  const int row = blockIdx.x, t = threadIdx.x;
  const size_t base = (size_t)row * DM + t * 4;
  const float4 a = *(const float4*)(attn + base);
  const float4 mo = *(const float4*)(modal1 + base);
  float av[4] = { a.x, a.y, a.z, a.w };
  float x[4] = { a.x + mo.x, a.y + mo.y, a.z + mo.z, a.w + mo.w };
  float s = 0.f, q = 0.f;
#pragma unroll
  for (int i = 0; i < 4; ++i) { s += x[i]; q += x[i] * x[i]; }
#pragma unroll
  for (int m = 1; m < 64; m <<= 1) { s += __shfl_xor(s, m, 64); q += __shfl_xor(q, m, 64); }
  if ((t & 63) == 0) { red[t >> 6] = s; red[2 + (t >> 6)] = q; }
  __syncthreads();
  s = red[0] + red[1]; q = red[2] + red[3];
  const float mu = s * (1.0f / DM);
  const float rinv = rsqrtf(q * (1.0f / DM) - mu * mu + 1e-5f);
  const int c = t * 4;
  const float4 G1 = *(const float4*)(g1 + c), B1 = *(const float4*)(b1 + c);
  const float gg1[4] = { G1.x, G1.y, G1.z, G1.w }, bb1[4] = { B1.x, B1.y, B1.z, B1.w };
  float y[4];
  float s2 = 0.f, q2 = 0.f;
#pragma unroll
  for (int i = 0; i < 4; ++i) {
    y[i] = av[i] + (x[i] - mu) * rinv * gg1[i] + bb1[i];
    s2 += y[i]; q2 += y[i] * y[i];
  }
#pragma unroll
  for (int m = 1; m < 64; m <<= 1) { s2 += __shfl_xor(s2, m, 64); q2 += __shfl_xor(q2, m, 64); }
  __syncthreads();
  if ((t & 63) == 0) { red[t >> 6] = s2; red[2 + (t >> 6)] = q2; }
  __syncthreads();
  s2 = red[0] + red[1]; q2 = red[2] + red[3];
  const float mu2 = s2 * (1.0f / DM);
  const float rinv2 = rsqrtf(q2 * (1.0f / DM) - mu2 * mu2 + 1e-5f);
  const float4 G2 = *(const float4*)(g2 + c), B2 = *(const float4*)(b2 + c);
  float4 o;
  o.x = (y[0] - mu2) * rinv2 * G2.x + B2.x;
  o.y = (y[1] - mu2) * rinv2 * G2.y + B2.y;
  o.z = (y[2] - mu2) * rinv2 * G2.z + B2.z;
  o.w = (y[3] - mu2) * rinv2 * G2.w + B2.w;
  *(float4*)(out + base) = o;
}

extern "C" void kernel_launch(void* const* d_in, const int* in_sizes, int n_in,
                              void* d_out, int out_size, void* d_ws, size_t ws_size,
                              hipStream_t stream) {
  const float* modal1 = (const float*)d_in[0];
  const float* modal2 = (const float*)d_in[1];
  const int*   m1     = (const int*)d_in[2];
  const int*   m2     = (const int*)d_in[3];
  const float* Wq     = (const float*)d_in[4];
  const float* bq     = (const float*)d_in[5];
  const float* Wkv    = (const float*)d_in[6];
  const float* bkv    = (const float*)d_in[7];
  const float* g1     = (const float*)d_in[8];
  const float* b1     = (const float*)d_in[9];
  // d_in[10..13] = W1,b1,W2,b2 -> FFN output is discarded by the reference; skip.
  const float* g2     = (const float*)d_in[14];
  const float* b2     = (const float*)d_in[15];
  float* out = (float*)d_out;

  char* ws = (char*)d_ws;
  unsigned short* q_bf  = (unsigned short*)(ws);                 //  8 MB
  unsigned short* k_bf  = (unsigned short*)(ws + 8388608);       //  8 MB
  unsigned short* kt_bf = (unsigned short*)(ws + 16777216);      //  8 MB
  unsigned short* wqt   = (unsigned short*)(ws + 25165824);      // 512 KB
  unsigned short* wkt   = (unsigned short*)(ws + 25690112);      // 512 KB
  float*          attn  = (float*)(ws + 26214400);               // 16 MB

  dim3 tb(32, 8);
  wtrans<<<dim3(16, 16), tb, 0, stream>>>(Wq, wqt);
  wtrans<<<dim3(16, 16), tb, 0, stream>>>(Wkv, wkt);
  proj_gemm<<<dim3(64, 4), 256, 0, stream>>>(modal1, wqt, bq, q_bf, nullptr);
  proj_gemm<<<dim3(64, 4), 256, 0, stream>>>(modal2, wkt, bkv, k_bf, kt_bf);
  flash_attn<<<dim3(32, 32), 256, 0, stream>>>(q_bf, k_bf, kt_bf, m1, m2, attn);
  ln_fused<<<dim3(8192), 128, 0, stream>>>(attn, modal1, g1, b1, g2, b2, out);
}

// Round 3
// 205.756 us; speedup vs baseline: 1.3357x; 1.3357x over previous
//
#include <hip/hip_runtime.h>
#include <hip/hip_bf16.h>

#define BSZ 4
#define S1v 2048
#define S2v 2048
#define DM 512
#define NH 8
#define HD 64
#define SCALE 0.044194173824159216f
#define L2E 1.4426950408889634f
#define SC_L2E (0.044194173824159216f * 1.4426950408889634f)
#define CBIAS 0.0028152f   /* log2(1+2^-9): centers truncating bf16 pack */
#define NEGB (-1e30f)

typedef __bf16 bf16x8 __attribute__((ext_vector_type(8)));
typedef float f32x4 __attribute__((ext_vector_type(4)));

__device__ __forceinline__ unsigned short f2bf(float f) {
  union { float f; unsigned u; } v; v.f = f;
  unsigned r = v.u + 0x7FFFu + ((v.u >> 16) & 1u);
  return (unsigned short)(r >> 16);
}
__device__ __forceinline__ unsigned asu(float f) {
  union { float f; unsigned u; } v; v.f = f; return v.u;
}

// ---------------- weight transpose + cast: Wt[n][k] = bf16(W[k][n]) ------------
__global__ __launch_bounds__(256)
void wtrans(const float* __restrict__ W, unsigned short* __restrict__ Wt) {
  __shared__ float tile[32][33];
  const int tx = threadIdx.x, ty = threadIdx.y;     // block (32,8)
  const int n0 = blockIdx.x * 32, k0 = blockIdx.y * 32;
#pragma unroll
  for (int i = 0; i < 32; i += 8)
    tile[ty + i][tx] = W[(size_t)(k0 + ty + i) * DM + n0 + tx];
  __syncthreads();
#pragma unroll
  for (int i = 0; i < 32; i += 8)
    Wt[(size_t)(n0 + ty + i) * DM + k0 + tx] = f2bf(tile[tx][ty + i]);
}

// ---------------- projection GEMM: Y(bf16)[8192x512] = X(f32) @ W + bias -------
__global__ __launch_bounds__(256)
void proj_gemm(const float* __restrict__ X, const unsigned short* __restrict__ Wt,
               const float* __restrict__ bias, unsigned short* __restrict__ Y) {
  __shared__ unsigned short Xs[128][72];
  __shared__ unsigned short Ws[128][72];
  const int tid = threadIdx.x;
  const int wv = tid >> 6, lane = tid & 63;
  const int ln = lane & 15, qd = lane >> 4, q8 = qd * 8;
  const int wm = (wv >> 1) * 64, wn = (wv & 1) * 64;
  const int m0 = blockIdx.x * 128, n0 = blockIdx.y * 128;
  f32x4 acc[4][4] = {};
  for (int k0 = 0; k0 < DM; k0 += 64) {
    __syncthreads();
#pragma unroll
    for (int i = 0; i < 8; ++i) {                   // X tile 128x64 f32 -> bf16
      int cid = tid + i * 256;
      int r = cid >> 4, c4 = (cid & 15) * 4;
      const float4 v = *(const float4*)(X + (size_t)(m0 + r) * DM + k0 + c4);
      ushort4 bv;
      bv.x = f2bf(v.x); bv.y = f2bf(v.y); bv.z = f2bf(v.z); bv.w = f2bf(v.w);
      *(ushort4*)&Xs[r][c4] = bv;
    }
#pragma unroll
    for (int i = 0; i < 4; ++i) {                   // Wt tile 128x64 bf16 copy
      int cid = tid + i * 256;
      int r = cid >> 3, ch = (cid & 7) * 8;
      *(uint4*)&Ws[r][ch] = *(const uint4*)(Wt + (size_t)(n0 + r) * DM + k0 + ch);
    }
    __syncthreads();
#pragma unroll
    for (int kk = 0; kk < 2; ++kk) {
      bf16x8 aF[4], bF[4];
#pragma unroll
      for (int i = 0; i < 4; ++i)
        aF[i] = *(const bf16x8*)&Xs[wm + 16 * i + ln][kk * 32 + q8];
#pragma unroll
      for (int j = 0; j < 4; ++j)
        bF[j] = *(const bf16x8*)&Ws[wn + 16 * j + ln][kk * 32 + q8];
#pragma unroll
      for (int i = 0; i < 4; ++i)
#pragma unroll
        for (int j = 0; j < 4; ++j)
          acc[i][j] = __builtin_amdgcn_mfma_f32_16x16x32_bf16(aF[i], bF[j], acc[i][j], 0, 0, 0);
    }
  }
#pragma unroll
  for (int i = 0; i < 4; ++i)
#pragma unroll
    for (int j = 0; j < 4; ++j) {
      const int n = n0 + wn + 16 * j + ln;
      const float bb = bias[n];
#pragma unroll
      for (int r = 0; r < 4; ++r) {
        const int m = m0 + wm + 16 * i + qd * 4 + r;
        Y[(size_t)m * DM + n] = f2bf(acc[i][j][r] + bb);
      }
    }
}

// ---------------- K^T builder with k-permutation baked in ----------------------
// Kt[(bh*64+d)][s_blk*128 + c'] = K[b][s_blk*128 + sigma(c')][h*64+d]
// sigma(c') = 16*(c'&7) + (c'>>3); matches the P-store layout in flash_attn.
__global__ __launch_bounds__(256)
void ktrans(const unsigned short* __restrict__ K, unsigned short* __restrict__ Kt) {
  __shared__ unsigned short T[128][72];
  const int tid = threadIdx.x;
  const int bh = blockIdx.y, b = bh >> 3, h = bh & 7;
  const int s0 = blockIdx.x * 128;
#pragma unroll
  for (int i = 0; i < 4; ++i) {                     // load tile [128 s][64 d]
    int cid = tid + i * 256;
    int r = cid >> 3, ch = (cid & 7) * 8;
    *(uint4*)&T[r][ch] =
        *(const uint4*)(K + (size_t)(b * S2v + s0 + r) * DM + h * HD + ch);
  }
  __syncthreads();
#pragma unroll
  for (int i = 0; i < 4; ++i) {                     // write [64 d][128 c']
    int cid = tid + i * 256;
    int d = cid >> 4, a = cid & 15;                 // c' = a*8 + k
    ushort4 v0, v1;
    v0.x = T[16 * 0 + a][d]; v0.y = T[16 * 1 + a][d];
    v0.z = T[16 * 2 + a][d]; v0.w = T[16 * 3 + a][d];
    v1.x = T[16 * 4 + a][d]; v1.y = T[16 * 5 + a][d];
    v1.z = T[16 * 6 + a][d]; v1.w = T[16 * 7 + a][d];
    unsigned short* o = Kt + ((size_t)(bh * HD + d)) * (size_t)S2v + s0 + a * 8;
    *(ushort4*)o = v0;
    *(ushort4*)(o + 4) = v1;
  }
}

// ---------------- flash attention (V = K), masked, static softmax --------------
// grid (S1/128, BSZ*NH), block 256: 4 waves x 32 Q-rows (2 subtiles of 16).
// No LDS union; Ps rows 136 shorts (272 B, 16B-aligned for b128); explicit
// lgkmcnt(0)+memory-clobber between P-pack stores and A-fragment loads.
__global__ __launch_bounds__(256, 2)
void flash_attn(const unsigned short* __restrict__ Qb, const unsigned short* __restrict__ Kb,
                const unsigned short* __restrict__ Kt, const int* __restrict__ m1,
                const int* __restrict__ m2, float* __restrict__ attn) {
  __shared__ unsigned short Ks[128][72];
  __shared__ unsigned short Vts[64][136];
  __shared__ unsigned short Ps[4][32][136];
  __shared__ int m2s[128];

  const int tid = threadIdx.x;
  const int wv = tid >> 6, lane = tid & 63;
  const int ln = lane & 15, qd = lane >> 4, q8 = qd * 8;
  const int bh = blockIdx.y;
  const int b = bh >> 3, h = bh & 7;
  const int q0 = blockIdx.x * 128;

  // Q fragments straight from global (one-time, L2-warm from proj_gemm)
  bf16x8 aQ[2][2];
#pragma unroll
  for (int t = 0; t < 2; ++t) {
    const size_t rbase =
        ((size_t)(b * S1v + q0 + wv * 32 + t * 16 + ln)) * DM + h * HD;
    aQ[t][0] = *(const bf16x8*)(Qb + rbase + q8);
    aQ[t][1] = *(const bf16x8*)(Qb + rbase + 32 + q8);
  }

  float acoef[2][4];                                // 0 if m1==0 (uniform row)
#pragma unroll
  for (int t = 0; t < 2; ++t)
#pragma unroll
    for (int r = 0; r < 4; ++r)
      acoef[t][r] = (m1[b * S1v + q0 + wv * 32 + t * 16 + qd * 4 + r] == 0) ? 0.f : 1.f;

  float lrow[2][4] = {};
  f32x4 O[2][4] = {};

  for (int s0 = 0; s0 < S2v; s0 += 128) {
    __syncthreads();
#pragma unroll
    for (int i = 0; i < 4; ++i) {                   // K tile 128x64
      int cid = tid + i * 256;
      int r = cid >> 3, ch = (cid & 7) * 8;
      *(uint4*)&Ks[r][ch] =
          *(const uint4*)(Kb + ((size_t)(b * S2v + s0 + r)) * DM + h * HD + ch);
    }
#pragma unroll
    for (int i = 0; i < 4; ++i) {                   // V^T tile 64x128 (k-permuted)
      int cid = tid + i * 256;
      int r = cid >> 4, ch = (cid & 15) * 8;
      *(uint4*)&Vts[r][ch] =
          *(const uint4*)(Kt + ((size_t)(bh * HD + r)) * (size_t)S2v + s0 + ch);
    }
    if (tid < 128) m2s[tid] = m2[b * S2v + s0 + tid];
    __syncthreads();

    // S = Q K^T : two 16-row subtiles share the K fragments
    f32x4 sc[2][8];
#pragma unroll
    for (int j = 0; j < 8; ++j) {
      const bf16x8 b0 = *(const bf16x8*)&Ks[16 * j + ln][q8];
      const bf16x8 b1 = *(const bf16x8*)&Ks[16 * j + ln][32 + q8];
#pragma unroll
      for (int t = 0; t < 2; ++t) {
        f32x4 z = {};
        z = __builtin_amdgcn_mfma_f32_16x16x32_bf16(aQ[t][0], b0, z, 0, 0, 0);
        sc[t][j] = __builtin_amdgcn_mfma_f32_16x16x32_bf16(aQ[t][1], b1, z, 0, 0, 0);
      }
    }

    float moff[8];
#pragma unroll
    for (int j = 0; j < 8; ++j)
      moff[j] = (m2s[16 * j + ln] != 0) ? 0.f : NEGB;

    // p = exp2( a * (sc*SC_L2E + moff) + CBIAS ); masked->0, uniform rows->2^CBIAS
#pragma unroll
    for (int t = 0; t < 2; ++t)
#pragma unroll
      for (int j = 0; j < 8; ++j)
#pragma unroll
        for (int r = 0; r < 4; ++r) {
          const float e = fmaf(acoef[t][r], fmaf(sc[t][j][r], SC_L2E, moff[j]), CBIAS);
          const float p = __builtin_amdgcn_exp2f(e);
          lrow[t][r] += p;
          sc[t][j][r] = p;
        }

    // pack: row q, cols c' = ln*8 .. ln*8+7  (one ds_write_b128 per (t,r))
#pragma unroll
    for (int t = 0; t < 2; ++t)
#pragma unroll
      for (int r = 0; r < 4; ++r) {
        uint4 dw;
        dw.x = __builtin_amdgcn_perm(asu(sc[t][1][r]), asu(sc[t][0][r]), 0x07060302u);
        dw.y = __builtin_amdgcn_perm(asu(sc[t][3][r]), asu(sc[t][2][r]), 0x07060302u);
        dw.z = __builtin_amdgcn_perm(asu(sc[t][5][r]), asu(sc[t][4][r]), 0x07060302u);
        dw.w = __builtin_amdgcn_perm(asu(sc[t][7][r]), asu(sc[t][6][r]), 0x07060302u);
        *(uint4*)&Ps[wv][t * 16 + qd * 4 + r][ln * 8] = dw;
      }
    // order + drain the P stores before the A-fragment reads (wave-private tile)
    __asm__ volatile("s_waitcnt lgkmcnt(0)" ::: "memory");

    // O += P V : subtiles share the V fragments
#pragma unroll
    for (int kk = 0; kk < 4; ++kk) {
      const bf16x8 aP0 = *(const bf16x8*)&Ps[wv][ln][kk * 32 + q8];
      const bf16x8 aP1 = *(const bf16x8*)&Ps[wv][16 + ln][kk * 32 + q8];
#pragma unroll
      for (int jn = 0; jn < 4; ++jn) {
        const bf16x8 bV = *(const bf16x8*)&Vts[16 * jn + ln][kk * 32 + q8];
        O[0][jn] = __builtin_amdgcn_mfma_f32_16x16x32_bf16(aP0, bV, O[0][jn], 0, 0, 0);
        O[1][jn] = __builtin_amdgcn_mfma_f32_16x16x32_bf16(aP1, bV, O[1][jn], 0, 0, 0);
      }
    }
  }

#pragma unroll
  for (int t = 0; t < 2; ++t)
#pragma unroll
    for (int r = 0; r < 4; ++r) {
      float l = lrow[t][r];
#pragma unroll
      for (int msk = 1; msk < 16; msk <<= 1) l += __shfl_xor(l, msk, 64);
      const float inv = l > 0.f ? 1.0f / l : 0.f;
      const int m = q0 + wv * 32 + t * 16 + qd * 4 + r;
#pragma unroll
      for (int jn = 0; jn < 4; ++jn)
        attn[((size_t)(b * S1v + m)) * DM + h * HD + 16 * jn + ln] = O[t][jn][r] * inv;
    }
}

// ---------------- fused LN2(attn + LN1(attn + modal1)) ------------------------
__global__ __launch_bounds__(128)
void ln_fused(const float* __restrict__ attn, const float* __restrict__ modal1,
              const float* __restrict__ g1, const float* __restrict__ b1,
              const float* __restrict__ g2, const float* __restrict__ b2,
              float* __restrict__ out) {
  __shared__ float red[4];
  const int row = blockIdx.x, t = threadIdx.x;
  const size_t base = (size_t)row * DM + t * 4;
  const float4 a = *(const float4*)(attn + base);
  const float4 mo = *(const float4*)(modal1 + base);
  float av[4] = { a.x, a.y, a.z, a.w };
  float x[4] = { a.x + mo.x, a.y + mo.y, a.z + mo.z, a.w + mo.w };
  float s = 0.f, q = 0.f;
#pragma unroll
  for (int i = 0; i < 4; ++i) { s += x[i]; q += x[i] * x[i]; }
#pragma unroll
  for (int m = 1; m < 64; m <<= 1) { s += __shfl_xor(s, m, 64); q += __shfl_xor(q, m, 64); }
  if ((t & 63) == 0) { red[t >> 6] = s; red[2 + (t >> 6)] = q; }
  __syncthreads();
  s = red[0] + red[1]; q = red[2] + red[3];
  const float mu = s * (1.0f / DM);
  const float rinv = rsqrtf(q * (1.0f / DM) - mu * mu + 1e-5f);
  const int c = t * 4;
  const float4 G1 = *(const float4*)(g1 + c), B1 = *(const float4*)(b1 + c);
  const float gg1[4] = { G1.x, G1.y, G1.z, G1.w }, bb1[4] = { B1.x, B1.y, B1.z, B1.w };
  float y[4];
  float s2 = 0.f, q2 = 0.f;
#pragma unroll
  for (int i = 0; i < 4; ++i) {
    y[i] = av[i] + (x[i] - mu) * rinv * gg1[i] + bb1[i];
    s2 += y[i]; q2 += y[i] * y[i];
  }
#pragma unroll
  for (int m = 1; m < 64; m <<= 1) { s2 += __shfl_xor(s2, m, 64); q2 += __shfl_xor(q2, m, 64); }
  __syncthreads();
  if ((t & 63) == 0) { red[t >> 6] = s2; red[2 + (t >> 6)] = q2; }
  __syncthreads();
  s2 = red[0] + red[1]; q2 = red[2] + red[3];
  const float mu2 = s2 * (1.0f / DM);
  const float rinv2 = rsqrtf(q2 * (1.0f / DM) - mu2 * mu2 + 1e-5f);
  const float4 G2 = *(const float4*)(g2 + c), B2 = *(const float4*)(b2 + c);
  float4 o;
  o.x = (y[0] - mu2) * rinv2 * G2.x + B2.x;
  o.y = (y[1] - mu2) * rinv2 * G2.y + B2.y;
  o.z = (y[2] - mu2) * rinv2 * G2.z + B2.z;
  o.w = (y[3] - mu2) * rinv2 * G2.w + B2.w;
  *(float4*)(out + base) = o;
}

extern "C" void kernel_launch(void* const* d_in, const int* in_sizes, int n_in,
                              void* d_out, int out_size, void* d_ws, size_t ws_size,
                              hipStream_t stream) {
  const float* modal1 = (const float*)d_in[0];
  const float* modal2 = (const float*)d_in[1];
  const int*   m1     = (const int*)d_in[2];
  const int*   m2     = (const int*)d_in[3];
  const float* Wq     = (const float*)d_in[4];
  const float* bq     = (const float*)d_in[5];
  const float* Wkv    = (const float*)d_in[6];
  const float* bkv    = (const float*)d_in[7];
  const float* g1     = (const float*)d_in[8];
  const float* b1     = (const float*)d_in[9];
  // d_in[10..13] = FFN weights -> output discarded by the reference; skipped.
  const float* g2     = (const float*)d_in[14];
  const float* b2     = (const float*)d_in[15];
  float* out = (float*)d_out;

  char* ws = (char*)d_ws;
  unsigned short* q_bf  = (unsigned short*)(ws);                 //  8 MB
  unsigned short* k_bf  = (unsigned short*)(ws + 8388608);       //  8 MB
  unsigned short* kt_bf = (unsigned short*)(ws + 16777216);      //  8 MB
  unsigned short* wqt   = (unsigned short*)(ws + 25165824);      // 512 KB
  unsigned short* wkt   = (unsigned short*)(ws + 25690112);      // 512 KB
  float*          attn  = (float*)(ws + 26214400);               // 16 MB

  dim3 tb(32, 8);
  wtrans<<<dim3(16, 16), tb, 0, stream>>>(Wq, wqt);
  wtrans<<<dim3(16, 16), tb, 0, stream>>>(Wkv, wkt);
  proj_gemm<<<dim3(64, 4), 256, 0, stream>>>(modal1, wqt, bq, q_bf);
  proj_gemm<<<dim3(64, 4), 256, 0, stream>>>(modal2, wkt, bkv, k_bf);
  ktrans<<<dim3(16, 32), 256, 0, stream>>>(k_bf, kt_bf);
  flash_attn<<<dim3(16, 32), 256, 0, stream>>>(q_bf, k_bf, kt_bf, m1, m2, attn);
  ln_fused<<<dim3(8192), 128, 0, stream>>>(attn, modal1, g1, b1, g2, b2, out);
}